// Round 1
// baseline (370.200 us; speedup 1.0000x reference)
//
#include <hip/hip_runtime.h>
#include <hip/hip_bf16.h>

#define BN_EPS 1e-5f

typedef short bf16x8 __attribute__((ext_vector_type(8)));
typedef float f32x4 __attribute__((ext_vector_type(4)));

static __device__ __forceinline__ unsigned short f2bf(float f) {
    unsigned u = __float_as_uint(f);
    unsigned r = (u + 0x7FFF + ((u >> 16) & 1)) >> 16;
    return (unsigned short)r;
}
static __device__ __forceinline__ float bf2f(unsigned short s) {
    return __uint_as_float((unsigned)s << 16);
}
__device__ __forceinline__ int pad4i(int c) { return (c + 3) & ~3; }

#define BIN_SHIFT 9
#define BIN_NODES 512
#define P1_CHUNK 8192
#define IMG_CAP 12288

// generic single-block exclusive scan (m <= 1024), in-place safe; out[m]=total
__global__ void scan_block_exclusive(const int* __restrict__ in, int* __restrict__ out, int m) {
    __shared__ int sd[256];
    int t = threadIdx.x;
    int base = t * 4;
    int v0 = (base + 0 < m) ? in[base + 0] : 0;
    int v1 = (base + 1 < m) ? in[base + 1] : 0;
    int v2 = (base + 2 < m) ? in[base + 2] : 0;
    int v3 = (base + 3 < m) ? in[base + 3] : 0;
    int tsum = v0 + v1 + v2 + v3;
    sd[t] = tsum;
    __syncthreads();
    for (int off = 1; off < 256; off <<= 1) {
        int x = (t >= off) ? sd[t - off] : 0;
        __syncthreads();
        sd[t] += x;
        __syncthreads();
    }
    int excl = sd[t] - tsum;
    if (base + 0 < m) out[base + 0] = excl;
    if (base + 1 < m) out[base + 1] = excl + v0;
    if (base + 2 < m) out[base + 2] = excl + v0 + v1;
    if (base + 3 < m) out[base + 3] = excl + v0 + v1 + v2;
    if (t == 255) out[m] = sd[255];
}

// ---------------- phase 1: partition edges into fixed-capacity 512-node bins
// Each bin b owns ebuf[b*ecap .. (b+1)*ecap). No histogram prepass / no bin
// scan needed: bincur[b] is the running fill cursor (zeroed by memset).
__global__ __launch_bounds__(256) void phase1_kernel(
        const int* __restrict__ src, const int* __restrict__ dst,
        int* __restrict__ bincur, int* __restrict__ ebuf, int e, int ecap) {
    __shared__ int hist[256], base[256], cur[256];
    int t = threadIdx.x;
    int c0 = blockIdx.x * P1_CHUNK;
    int iend = c0 + P1_CHUNK; if (iend > e) iend = e;
    hist[t] = 0;
    __syncthreads();
    for (int i = c0 + t; i < iend; i += 256)
        atomicAdd(&hist[dst[i] >> BIN_SHIFT], 1);
    __syncthreads();
    if (hist[t] > 0)
        base[t] = t * ecap + atomicAdd(&bincur[t], hist[t]);
    cur[t] = 0;
    __syncthreads();
    for (int i = c0 + t; i < iend; i += 256) {
        int s = src[i], d = dst[i];
        int b = d >> BIN_SHIFT;
        int r = atomicAdd(&cur[b], 1);
        int p = base[b] + r;
        if (p < (b + 1) * ecap)                     // capacity guard (never in practice)
            ebuf[p] = s | ((d & (BIN_NODES - 1)) << 17);
    }
}

// ---------------- per-node counts + dinv + in-bin padded row offsets --------
// Also computes per-bin padded total (binpad) for the tiny bin-base scan,
// and zeroes the sentinel row of h_a (fused).
__global__ __launch_bounds__(256) void bincount_kernel(
        const int* __restrict__ ebuf, const int* __restrict__ bincur, int ecap,
        float* __restrict__ dinv, int* __restrict__ row_local,
        int* __restrict__ binpad, unsigned short* __restrict__ ha_sent, int n) {
    __shared__ int c512[BIN_NODES];
    __shared__ int sd[256];
    int b = blockIdx.x, t = threadIdx.x;
    if (b == 0 && t < 64) ha_sent[t] = 0;           // zero sentinel row (fused)
    c512[t] = 0; c512[t + 256] = 0;
    __syncthreads();
    int cnt_b = bincur[b]; if (cnt_b > ecap) cnt_b = ecap;
    int e0 = b * ecap, e1 = e0 + cnt_b;
    for (int j = e0 + t; j < e1; j += 256)
        atomicAdd(&c512[ebuf[j] >> 17], 1);
    __syncthreads();
    int n0 = b * BIN_NODES;
    // dinv (counts +1 for self-loop)
    for (int k = t; k < BIN_NODES; k += 256) {
        int i = n0 + k;
        if (i < n) dinv[i] = rsqrtf((float)(c512[k] + 1));
    }
    // exclusive prefix scan of pad4(count) over 512 nodes (2 per thread)
    int v0 = pad4i(c512[2 * t]);
    int v1 = pad4i(c512[2 * t + 1]);
    int tsum = v0 + v1;
    sd[t] = tsum;
    __syncthreads();
    for (int off = 1; off < 256; off <<= 1) {
        int x = (t >= off) ? sd[t - off] : 0;
        __syncthreads();
        sd[t] += x;
        __syncthreads();
    }
    int excl = sd[t] - tsum;
    row_local[n0 + 2 * t]     = excl;
    row_local[n0 + 2 * t + 1] = excl + v0;
    if (t == 255) binpad[b] = sd[255];
}

// ---------------- phase 2: per-bin CSR build in LDS, coalesced write-out ----
// Also finalizes global row_start[i] = binbase[b] + row_local[i].
__global__ __launch_bounds__(256) void phase2_kernel(
        const int* __restrict__ ebuf, const int* __restrict__ bincur, int ecap,
        const int* __restrict__ row_local, const int* __restrict__ binbase,
        int* __restrict__ row_start, int* __restrict__ csr,
        int* __restrict__ gcursor, int n, int nbins, int sentinel) {
    __shared__ int image[IMG_CAP];
    __shared__ int lcur[BIN_NODES];
    __shared__ int rl[BIN_NODES];
    int b = blockIdx.x, t = threadIdx.x;
    int n0 = b * BIN_NODES;
    int nloc = n - n0; if (nloc > BIN_NODES) nloc = BIN_NODES;
    int rb = binbase[b];
    int rspan = binbase[b + 1] - rb;
    int cnt_b = bincur[b]; if (cnt_b > ecap) cnt_b = ecap;
    int e0 = b * ecap, e1 = e0 + cnt_b;
    for (int k = t; k < BIN_NODES; k += 256) {
        rl[k] = row_local[n0 + k];
        lcur[k] = 0;
    }
    __syncthreads();
    for (int k = t; k < nloc; k += 256)             // finalize global row_start
        row_start[n0 + k] = rb + rl[k];
    if (b == 0 && t == 0) row_start[n] = binbase[nbins];
    if (rspan <= IMG_CAP) {
        for (int k = t; k < rspan; k += 256) image[k] = sentinel;
        __syncthreads();
        for (int j = e0 + t; j < e1; j += 256) {
            int en = ebuf[j];
            int s = en & 0x1FFFF;
            int dl = en >> 17;
            int pos = rl[dl] + atomicAdd(&lcur[dl], 1);
            image[pos] = s;
        }
        __syncthreads();
        for (int k = t; k < rspan; k += 256) csr[rb + k] = image[k];
    } else {                                        // statistically never
        for (int k = t; k < nloc; k += 256) gcursor[n0 + k] = 0;
        __syncthreads();
        for (int j = e0 + t; j < e1; j += 256) {
            int en = ebuf[j];
            int s = en & 0x1FFFF;
            int dl = en >> 17;
            int pos = rb + rl[dl] + atomicAdd(&gcursor[n0 + dl], 1);
            csr[pos] = s;
        }
        __syncthreads();
        for (int k = t; k < nloc; k += 256) {       // fill pads with sentinel
            int node = n0 + k;
            int start = rb + rl[k] + gcursor[node];
            int end = (k < BIN_NODES - 1) ? rb + rl[k + 1] : binbase[b + 1];
            for (int pos = start; pos < end; pos++) csr[pos] = sentinel;
        }
    }
}

// ---------------- MFMA linear: hs[N,64] = dinv[r] * (in[N,K] @ w[K,64]) ----
template<int K, bool BF16IN>
__global__ __launch_bounds__(256) void lin_mfma(const void* __restrict__ in_,
                                                const float* __restrict__ w,
                                                const float* __restrict__ dinv,
                                                unsigned short* __restrict__ outbf, int n) {
    constexpr int XS = K + 8;
    __shared__ unsigned short xs[64 * XS];
    __shared__ unsigned short wt[64 * XS];
    int t = threadIdx.x;
    int row0 = blockIdx.x * 64;
    int nrows = n - row0; if (nrows > 64) nrows = 64;

    {
        const float4* w4 = (const float4*)w;
        for (int idx = t; idx < K * 16; idx += 256) {
            int k = idx >> 4, c4 = (idx & 15) * 4;
            float4 v = w4[idx];
            wt[(c4 + 0) * XS + k] = f2bf(v.x);
            wt[(c4 + 1) * XS + k] = f2bf(v.y);
            wt[(c4 + 2) * XS + k] = f2bf(v.z);
            wt[(c4 + 3) * XS + k] = f2bf(v.w);
        }
    }
    if constexpr (BF16IN) {
        const uint4* in4 = (const uint4*)((const unsigned short*)in_ + (size_t)row0 * K);
        int total8 = nrows * (K / 8);
        for (int idx = t; idx < total8; idx += 256) {
            int r = idx / (K / 8), kk = idx - r * (K / 8);
            uint4 v = in4[idx];
            *(uint4*)&xs[r * XS + kk * 8] = v;
        }
    } else {
        const float4* in4 = (const float4*)((const float*)in_ + (size_t)row0 * K);
        int total4 = nrows * (K / 4);
        for (int idx = t; idx < total4; idx += 256) {
            int r = idx / (K / 4), kk = idx - r * (K / 4);
            float4 v = in4[idx];
            ushort4 s4;
            s4.x = f2bf(v.x); s4.y = f2bf(v.y); s4.z = f2bf(v.z); s4.w = f2bf(v.w);
            *(ushort4*)&xs[r * XS + kk * 4] = s4;
        }
    }
    __syncthreads();

    int lane = t & 63;
    int wid = t >> 6;
    int quad = lane >> 4;
    int l15 = lane & 15;

    f32x4 acc[4];
#pragma unroll
    for (int cg_ = 0; cg_ < 4; cg_++) acc[cg_] = (f32x4){0.f, 0.f, 0.f, 0.f};

    const unsigned short* xrow = &xs[(wid * 16 + l15) * XS + quad * 8];
#pragma unroll
    for (int kc = 0; kc < K / 32; kc++) {
        bf16x8 bfrag = *(const bf16x8*)(xrow + kc * 32);
#pragma unroll
        for (int cg_ = 0; cg_ < 4; cg_++) {
            bf16x8 afrag = *(const bf16x8*)&wt[(cg_ * 16 + l15) * XS + kc * 32 + quad * 8];
            acc[cg_] = __builtin_amdgcn_mfma_f32_16x16x32_bf16(afrag, bfrag, acc[cg_], 0, 0, 0);
        }
    }

    int grow = row0 + wid * 16 + l15;
    if (grow < n) {
        float dv = dinv[grow];
#pragma unroll
        for (int cg_ = 0; cg_ < 4; cg_++) {
            ushort4 st;
            st.x = f2bf(acc[cg_][0] * dv);
            st.y = f2bf(acc[cg_][1] * dv);
            st.z = f2bf(acc[cg_][2] * dv);
            st.w = f2bf(acc[cg_][3] * dv);
            *(ushort4*)&outbf[(size_t)grow * 64 + cg_ * 16 + quad * 4] = st;
        }
    }
}

// ---------------- aggregation + bias + BN + ReLU (uniform CSR walk) --------
// Rows are x4 padded (sentinel entries gather the zeroed sentinel row).
// i/rs/re/csr-entries scalarized via readfirstlane -> CSR reads go through
// the SMEM pipe; gathers use 32-bit voffset (1 VALU each).
__global__ __launch_bounds__(256) void agg_kernel(
        const unsigned short* __restrict__ hs, const int* __restrict__ row_start,
        const int* __restrict__ csr, const float* __restrict__ dinv,
        const float* __restrict__ bias, const float* __restrict__ gam,
        const float* __restrict__ bet, const float* __restrict__ mu,
        const float* __restrict__ var,
        unsigned short* __restrict__ out, int n) {
    int iw = blockIdx.x * 4 + (threadIdx.x >> 6);
    unsigned lane = threadIdx.x & 63;
    if (iw >= n) return;                            // wave-uniform exit
    int i = __builtin_amdgcn_readfirstlane(iw);
    float acc = bf2f(hs[((unsigned)i << 6) + lane]); // self-loop (pre-scaled)
    int rs = __builtin_amdgcn_readfirstlane(row_start[i]);
    int re = __builtin_amdgcn_readfirstlane(row_start[i + 1]);  // x4 padded
    int j = rs;
    for (; j + 16 <= re; j += 16) {
        int s0 = __builtin_amdgcn_readfirstlane(csr[j + 0]);
        int s1 = __builtin_amdgcn_readfirstlane(csr[j + 1]);
        int s2 = __builtin_amdgcn_readfirstlane(csr[j + 2]);
        int s3 = __builtin_amdgcn_readfirstlane(csr[j + 3]);
        int s4 = __builtin_amdgcn_readfirstlane(csr[j + 4]);
        int s5 = __builtin_amdgcn_readfirstlane(csr[j + 5]);
        int s6 = __builtin_amdgcn_readfirstlane(csr[j + 6]);
        int s7 = __builtin_amdgcn_readfirstlane(csr[j + 7]);
        int s8 = __builtin_amdgcn_readfirstlane(csr[j + 8]);
        int s9 = __builtin_amdgcn_readfirstlane(csr[j + 9]);
        int sA = __builtin_amdgcn_readfirstlane(csr[j + 10]);
        int sB = __builtin_amdgcn_readfirstlane(csr[j + 11]);
        int sC = __builtin_amdgcn_readfirstlane(csr[j + 12]);
        int sD = __builtin_amdgcn_readfirstlane(csr[j + 13]);
        int sE = __builtin_amdgcn_readfirstlane(csr[j + 14]);
        int sF = __builtin_amdgcn_readfirstlane(csr[j + 15]);
        float h0 = bf2f(hs[((unsigned)s0 << 6) + lane]);
        float h1 = bf2f(hs[((unsigned)s1 << 6) + lane]);
        float h2 = bf2f(hs[((unsigned)s2 << 6) + lane]);
        float h3 = bf2f(hs[((unsigned)s3 << 6) + lane]);
        float h4 = bf2f(hs[((unsigned)s4 << 6) + lane]);
        float h5 = bf2f(hs[((unsigned)s5 << 6) + lane]);
        float h6 = bf2f(hs[((unsigned)s6 << 6) + lane]);
        float h7 = bf2f(hs[((unsigned)s7 << 6) + lane]);
        float h8 = bf2f(hs[((unsigned)s8 << 6) + lane]);
        float h9 = bf2f(hs[((unsigned)s9 << 6) + lane]);
        float hA = bf2f(hs[((unsigned)sA << 6) + lane]);
        float hB = bf2f(hs[((unsigned)sB << 6) + lane]);
        float hC = bf2f(hs[((unsigned)sC << 6) + lane]);
        float hD = bf2f(hs[((unsigned)sD << 6) + lane]);
        float hE = bf2f(hs[((unsigned)sE << 6) + lane]);
        float hF = bf2f(hs[((unsigned)sF << 6) + lane]);
        acc += (((h0 + h1) + (h2 + h3)) + ((h4 + h5) + (h6 + h7)))
             + (((h8 + h9) + (hA + hB)) + ((hC + hD) + (hE + hF)));
    }
    for (; j < re; j += 4) {
        int s0 = __builtin_amdgcn_readfirstlane(csr[j + 0]);
        int s1 = __builtin_amdgcn_readfirstlane(csr[j + 1]);
        int s2 = __builtin_amdgcn_readfirstlane(csr[j + 2]);
        int s3 = __builtin_amdgcn_readfirstlane(csr[j + 3]);
        float h0 = bf2f(hs[((unsigned)s0 << 6) + lane]);
        float h1 = bf2f(hs[((unsigned)s1 << 6) + lane]);
        float h2 = bf2f(hs[((unsigned)s2 << 6) + lane]);
        float h3 = bf2f(hs[((unsigned)s3 << 6) + lane]);
        acc += (h0 + h1) + (h2 + h3);
    }
    float agg = acc * dinv[i];
    float scale = gam[lane] * rsqrtf(var[lane] + BN_EPS);
    float r = (agg + bias[lane] - mu[lane]) * scale + bet[lane];
    out[((unsigned)i << 6) + lane] = f2bf(r > 0.f ? r : 0.f);
}

// ---------------- pool stage 1: node-parallel segmented sum (bf16 in) ------
#define POOL_CHUNK 64
__global__ __launch_bounds__(256) void pool_kernel(const unsigned short* __restrict__ h,
                                                   const int* __restrict__ batch,
                                                   float* __restrict__ pooled, int n) {
    int wid = blockIdx.x * 4 + (threadIdx.x >> 6);
    int lane = threadIdx.x & 63;
    int start = wid * POOL_CHUNK;
    if (start >= n) return;
    int end = start + POOL_CHUNK; if (end > n) end = n;
    int cur = batch[start];
    float acc = 0.f;
    for (int i = start; i < end; i++) {
        int b = batch[i];
        if (b != cur) {
            atomicAdd(&pooled[(size_t)cur * 64 + lane], acc);
            acc = 0.f; cur = b;
        }
        acc += bf2f(h[(size_t)i * 64 + lane]);
    }
    atomicAdd(&pooled[(size_t)cur * 64 + lane], acc);
}

// ---------------- pool stage 2: tiny MLP per graph ----------------
__global__ void mlp_kernel(const float* __restrict__ pooled,
                           const float* __restrict__ l1w, const float* __restrict__ l1b,
                           const float* __restrict__ l2w, const float* __restrict__ l2b,
                           float* __restrict__ out) {
    int g = blockIdx.x;
    int lane = threadIdx.x;
    __shared__ float p[64];
    __shared__ float h1[32];
    p[lane] = pooled[(size_t)g * 64 + lane];
    __syncthreads();
    if (lane < 32) {
        float a = l1b[lane];
#pragma unroll 8
        for (int k = 0; k < 64; k++) a += p[k] * l1w[k * 32 + lane];
        h1[lane] = a > 0.f ? a : 0.f;
    }
    __syncthreads();
    if (lane < 2) {
        float a = l2b[lane];
#pragma unroll 8
        for (int j = 0; j < 32; j++) a += h1[j] * l2w[j * 2 + lane];
        out[g * 2 + lane] = a;
    }
}

extern "C" void kernel_launch(void* const* d_in, const int* in_sizes, int n_in,
                              void* d_out, int out_size, void* d_ws, size_t ws_size,
                              hipStream_t stream) {
    const float* x     = (const float*)d_in[0];
    const int*   ei    = (const int*)d_in[1];
    const int*   batch = (const int*)d_in[2];
    const float* w0 = (const float*)d_in[3];
    const float* b0 = (const float*)d_in[4];
    const float* w1 = (const float*)d_in[5];
    const float* b1 = (const float*)d_in[6];
    const float* w2 = (const float*)d_in[7];
    const float* b2 = (const float*)d_in[8];
    const float* g0 = (const float*)d_in[9];
    const float* be0 = (const float*)d_in[10];
    const float* m0 = (const float*)d_in[11];
    const float* v0 = (const float*)d_in[12];
    const float* g1 = (const float*)d_in[13];
    const float* be1 = (const float*)d_in[14];
    const float* m1 = (const float*)d_in[15];
    const float* v1 = (const float*)d_in[16];
    const float* g2 = (const float*)d_in[17];
    const float* be2 = (const float*)d_in[18];
    const float* m2 = (const float*)d_in[19];
    const float* v2 = (const float*)d_in[20];
    const float* l1w = (const float*)d_in[21];
    const float* l1b = (const float*)d_in[22];
    const float* l2w = (const float*)d_in[23];
    const float* l2b = (const float*)d_in[24];
    float* out = (float*)d_out;

    const int N = in_sizes[2];
    const int E = in_sizes[1] / 2;
    const int G = out_size / 2;
    const int NBINS = (N + BIN_NODES - 1) / BIN_NODES;
    // fixed per-bin edge capacity: 2x the mean (+45 sigma for Poisson bins)
    int ECAP = ((2 * (E / NBINS)) + 1023) & ~1023;
    if (ECAP < 2048) ECAP = 2048;

    const int* src = ei;
    const int* dst = ei + E;

    // workspace layout
    char* p = (char*)d_ws;
    auto alloc = [&](size_t bytes) -> void* {
        void* r = (void*)p;
        p += (bytes + 255) & ~(size_t)255;
        return r;
    };
    const size_t CSR_CAP = (size_t)E + 4 * (size_t)N + 64;
    float* dinvp    = (float*)alloc((size_t)N * 4);
    int*   row_start= (int*)alloc((size_t)(N + 1) * 4);
    int*   row_local= (int*)alloc((size_t)NBINS * BIN_NODES * 4);
    int*   binpad   = (int*)alloc((size_t)NBINS * 4);
    int*   binbase  = (int*)alloc((size_t)(NBINS + 1) * 4);
    int*   gcursor  = (int*)alloc((size_t)N * 4);
    int*   bincur   = (int*)alloc((size_t)NBINS * 4);      // | contiguous zero
    float* pooled   = (float*)alloc((size_t)G * 64 * 4);   // | region
    char*  zero_end = p;
    int*   ebuf     = (int*)alloc((size_t)NBINS * ECAP * 4);
    int*   csr      = (int*)alloc(CSR_CAP * 4);
    unsigned short* h_a = (unsigned short*)alloc((size_t)(N + 1) * 64 * 2); // +sentinel row
    unsigned short* h_b = (unsigned short*)alloc((size_t)N * 64 * 2);
    (void)ws_size;

    // ---- graph preprocessing (4 launches + 1 memset) ----
    hipMemsetAsync(bincur, 0, (size_t)(zero_end - (char*)bincur), stream);
    const int nchunks = (E + P1_CHUNK - 1) / P1_CHUNK;
    phase1_kernel<<<nchunks, 256, 0, stream>>>(src, dst, bincur, ebuf, E, ECAP);
    bincount_kernel<<<NBINS, 256, 0, stream>>>(ebuf, bincur, ECAP, dinvp,
                                               row_local, binpad,
                                               h_a + (size_t)N * 64, N);
    scan_block_exclusive<<<1, 256, 0, stream>>>(binpad, binbase, NBINS);
    phase2_kernel<<<NBINS, 256, 0, stream>>>(ebuf, bincur, ECAP, row_local,
                                             binbase, row_start, csr,
                                             gcursor, N, NBINS, N);

    const int nblk = (N + 3) / 4;
    const int lblk = (N + 63) / 64;
    // ---- layer 0 ----
    lin_mfma<128, false><<<lblk, 256, 0, stream>>>(x, w0, dinvp, h_a, N);
    agg_kernel<<<nblk, 256, 0, stream>>>(h_a, row_start, csr, dinvp,
                                         b0, g0, be0, m0, v0, h_b, N);
    // ---- layer 1 ----
    lin_mfma<64, true><<<lblk, 256, 0, stream>>>(h_b, w1, dinvp, h_a, N);
    agg_kernel<<<nblk, 256, 0, stream>>>(h_a, row_start, csr, dinvp,
                                         b1, g1, be1, m1, v1, h_b, N);
    // ---- layer 2 ----
    lin_mfma<64, true><<<lblk, 256, 0, stream>>>(h_b, w2, dinvp, h_a, N);
    agg_kernel<<<nblk, 256, 0, stream>>>(h_a, row_start, csr, dinvp,
                                         b2, g2, be2, m2, v2, h_b, N);
    // ---- pool + MLP ----
    const int pwaves = (N + POOL_CHUNK - 1) / POOL_CHUNK;
    pool_kernel<<<(pwaves + 3) / 4, 256, 0, stream>>>(h_b, batch, pooled, N);
    mlp_kernel<<<G, 64, 0, stream>>>(pooled, l1w, l1b, l2w, l2b, out);
}

// Round 2
// 349.003 us; speedup vs baseline: 1.0607x; 1.0607x over previous
//
#include <hip/hip_runtime.h>
#include <hip/hip_bf16.h>

#define BN_EPS 1e-5f

typedef short bf16x8 __attribute__((ext_vector_type(8)));
typedef float f32x4 __attribute__((ext_vector_type(4)));

static __device__ __forceinline__ unsigned short f2bf(float f) {
    unsigned u = __float_as_uint(f);
    unsigned r = (u + 0x7FFF + ((u >> 16) & 1)) >> 16;
    return (unsigned short)r;
}
static __device__ __forceinline__ float bf2f(unsigned short s) {
    return __uint_as_float((unsigned)s << 16);
}
__device__ __forceinline__ int pad4i(int c) { return (c + 3) & ~3; }

#define BIN_SHIFT 9
#define BIN_NODES 512
#define P1_CHUNK 8192
#define P1_THREADS 1024
#define P1_PER_THREAD (P1_CHUNK / P1_THREADS)   // 8
#define IMG_CAP 12288
#define P2_THREADS 512

// generic single-block exclusive scan (m <= 1024), in-place safe; out[m]=total
__global__ void scan_block_exclusive(const int* __restrict__ in, int* __restrict__ out, int m) {
    __shared__ int sd[256];
    int t = threadIdx.x;
    int base = t * 4;
    int v0 = (base + 0 < m) ? in[base + 0] : 0;
    int v1 = (base + 1 < m) ? in[base + 1] : 0;
    int v2 = (base + 2 < m) ? in[base + 2] : 0;
    int v3 = (base + 3 < m) ? in[base + 3] : 0;
    int tsum = v0 + v1 + v2 + v3;
    sd[t] = tsum;
    __syncthreads();
    for (int off = 1; off < 256; off <<= 1) {
        int x = (t >= off) ? sd[t - off] : 0;
        __syncthreads();
        sd[t] += x;
        __syncthreads();
    }
    int excl = sd[t] - tsum;
    if (base + 0 < m) out[base + 0] = excl;
    if (base + 1 < m) out[base + 1] = excl + v0;
    if (base + 2 < m) out[base + 2] = excl + v0 + v1;
    if (base + 3 < m) out[base + 3] = excl + v0 + v1 + v2;
    if (t == 255) out[m] = sd[255];
}

// ---------------- phase 1: partition edges into fixed-capacity 512-node bins
// Each bin b owns ebuf[b*ecap .. (b+1)*ecap). bincur[b] is the running fill
// cursor (zeroed by memset). 1024 threads/block (16 waves) for latency hiding;
// dst values cached in registers across the two passes.
__global__ __launch_bounds__(P1_THREADS) void phase1_kernel(
        const int* __restrict__ src, const int* __restrict__ dst,
        int* __restrict__ bincur, int* __restrict__ ebuf, int e, int ecap) {
    __shared__ int hist[256], base[256], cur[256];
    int t = threadIdx.x;
    int c0 = blockIdx.x * P1_CHUNK;
    int iend = c0 + P1_CHUNK; if (iend > e) iend = e;
    if (t < 256) hist[t] = 0;
    __syncthreads();
    int dreg[P1_PER_THREAD];
#pragma unroll
    for (int u = 0; u < P1_PER_THREAD; u++) {
        int i = c0 + t + u * P1_THREADS;
        if (i < iend) {
            int d = dst[i];
            dreg[u] = d;
            atomicAdd(&hist[d >> BIN_SHIFT], 1);
        }
    }
    __syncthreads();
    if (t < 256) {
        if (hist[t] > 0)
            base[t] = t * ecap + atomicAdd(&bincur[t], hist[t]);
        cur[t] = 0;
    }
    __syncthreads();
#pragma unroll
    for (int u = 0; u < P1_PER_THREAD; u++) {
        int i = c0 + t + u * P1_THREADS;
        if (i < iend) {
            int s = src[i], d = dreg[u];
            int b = d >> BIN_SHIFT;
            int r = atomicAdd(&cur[b], 1);
            int p = base[b] + r;
            if (p < (b + 1) * ecap)                 // capacity guard (never in practice)
                ebuf[p] = s | ((d & (BIN_NODES - 1)) << 17);
        }
    }
}

// ---------------- per-node counts + dinv + in-bin padded row offsets --------
// Also computes per-bin padded total (binpad) for the tiny bin-base scan,
// and zeroes the sentinel row of h_a (fused). 1024 threads (16 waves).
__global__ __launch_bounds__(1024) void bincount_kernel(
        const int* __restrict__ ebuf, const int* __restrict__ bincur, int ecap,
        float* __restrict__ dinv, int* __restrict__ row_local,
        int* __restrict__ binpad, unsigned short* __restrict__ ha_sent, int n) {
    __shared__ int c512[BIN_NODES];
    __shared__ int sd[256];
    int b = blockIdx.x, t = threadIdx.x;
    if (b == 0 && t < 64) ha_sent[t] = 0;           // zero sentinel row (fused)
    if (t < BIN_NODES) c512[t] = 0;
    __syncthreads();
    int cnt_b = bincur[b]; if (cnt_b > ecap) cnt_b = ecap;
    int e0 = b * ecap, e1 = e0 + cnt_b;
    for (int j = e0 + t; j < e1; j += 1024)
        atomicAdd(&c512[ebuf[j] >> 17], 1);
    __syncthreads();
    int n0 = b * BIN_NODES;
    // dinv (counts +1 for self-loop)
    if (t < BIN_NODES) {
        int i = n0 + t;
        if (i < n) dinv[i] = rsqrtf((float)(c512[t] + 1));
    }
    // exclusive prefix scan of pad4(count) over 512 nodes (2 per lead thread)
    int v0 = 0, v1 = 0, tsum = 0;
    if (t < 256) {
        v0 = pad4i(c512[2 * t]);
        v1 = pad4i(c512[2 * t + 1]);
        tsum = v0 + v1;
        sd[t] = tsum;
    }
    __syncthreads();
    for (int off = 1; off < 256; off <<= 1) {
        int x = 0;
        if (t < 256 && t >= off) x = sd[t - off];
        __syncthreads();
        if (t < 256) sd[t] += x;
        __syncthreads();
    }
    if (t < 256) {
        int excl = sd[t] - tsum;
        row_local[n0 + 2 * t]     = excl;
        row_local[n0 + 2 * t + 1] = excl + v0;
        if (t == 255) binpad[b] = sd[255];
    }
}

// ---------------- phase 2: per-bin CSR build in LDS, coalesced write-out ----
// Also finalizes global row_start[i] = binbase[b] + row_local[i]. 512 thr.
__global__ __launch_bounds__(P2_THREADS) void phase2_kernel(
        const int* __restrict__ ebuf, const int* __restrict__ bincur, int ecap,
        const int* __restrict__ row_local, const int* __restrict__ binbase,
        int* __restrict__ row_start, int* __restrict__ csr,
        int* __restrict__ gcursor, int n, int nbins, int sentinel) {
    __shared__ int image[IMG_CAP];
    __shared__ int lcur[BIN_NODES];
    __shared__ int rl[BIN_NODES];
    int b = blockIdx.x, t = threadIdx.x;
    int n0 = b * BIN_NODES;
    int nloc = n - n0; if (nloc > BIN_NODES) nloc = BIN_NODES;
    int rb = binbase[b];
    int rspan = binbase[b + 1] - rb;
    int cnt_b = bincur[b]; if (cnt_b > ecap) cnt_b = ecap;
    int e0 = b * ecap, e1 = e0 + cnt_b;
    if (t < BIN_NODES) {
        rl[t] = row_local[n0 + t];
        lcur[t] = 0;
    }
    __syncthreads();
    for (int k = t; k < nloc; k += P2_THREADS)      // finalize global row_start
        row_start[n0 + k] = rb + rl[k];
    if (b == 0 && t == 0) row_start[n] = binbase[nbins];
    if (rspan <= IMG_CAP) {
        for (int k = t; k < rspan; k += P2_THREADS) image[k] = sentinel;
        __syncthreads();
        for (int j = e0 + t; j < e1; j += P2_THREADS) {
            int en = ebuf[j];
            int s = en & 0x1FFFF;
            int dl = en >> 17;
            int pos = rl[dl] + atomicAdd(&lcur[dl], 1);
            image[pos] = s;
        }
        __syncthreads();
        for (int k = t; k < rspan; k += P2_THREADS) csr[rb + k] = image[k];
    } else {                                        // statistically never
        for (int k = t; k < nloc; k += P2_THREADS) gcursor[n0 + k] = 0;
        __syncthreads();
        for (int j = e0 + t; j < e1; j += P2_THREADS) {
            int en = ebuf[j];
            int s = en & 0x1FFFF;
            int dl = en >> 17;
            int pos = rb + rl[dl] + atomicAdd(&gcursor[n0 + dl], 1);
            csr[pos] = s;
        }
        __syncthreads();
        for (int k = t; k < nloc; k += P2_THREADS) { // fill pads with sentinel
            int node = n0 + k;
            int start = rb + rl[k] + gcursor[node];
            int end = (k < BIN_NODES - 1) ? rb + rl[k + 1] : binbase[b + 1];
            for (int pos = start; pos < end; pos++) csr[pos] = sentinel;
        }
    }
}

// ---------------- MFMA linear: hs[N,64] = dinv[r] * (in[N,K] @ w[K,64]) ----
template<int K, bool BF16IN>
__global__ __launch_bounds__(256) void lin_mfma(const void* __restrict__ in_,
                                                const float* __restrict__ w,
                                                const float* __restrict__ dinv,
                                                unsigned short* __restrict__ outbf, int n) {
    constexpr int XS = K + 8;
    __shared__ unsigned short xs[64 * XS];
    __shared__ unsigned short wt[64 * XS];
    int t = threadIdx.x;
    int row0 = blockIdx.x * 64;
    int nrows = n - row0; if (nrows > 64) nrows = 64;

    {
        const float4* w4 = (const float4*)w;
        for (int idx = t; idx < K * 16; idx += 256) {
            int k = idx >> 4, c4 = (idx & 15) * 4;
            float4 v = w4[idx];
            wt[(c4 + 0) * XS + k] = f2bf(v.x);
            wt[(c4 + 1) * XS + k] = f2bf(v.y);
            wt[(c4 + 2) * XS + k] = f2bf(v.z);
            wt[(c4 + 3) * XS + k] = f2bf(v.w);
        }
    }
    if constexpr (BF16IN) {
        const uint4* in4 = (const uint4*)((const unsigned short*)in_ + (size_t)row0 * K);
        int total8 = nrows * (K / 8);
        for (int idx = t; idx < total8; idx += 256) {
            int r = idx / (K / 8), kk = idx - r * (K / 8);
            uint4 v = in4[idx];
            *(uint4*)&xs[r * XS + kk * 8] = v;
        }
    } else {
        const float4* in4 = (const float4*)((const float*)in_ + (size_t)row0 * K);
        int total4 = nrows * (K / 4);
        for (int idx = t; idx < total4; idx += 256) {
            int r = idx / (K / 4), kk = idx - r * (K / 4);
            float4 v = in4[idx];
            ushort4 s4;
            s4.x = f2bf(v.x); s4.y = f2bf(v.y); s4.z = f2bf(v.z); s4.w = f2bf(v.w);
            *(ushort4*)&xs[r * XS + kk * 4] = s4;
        }
    }
    __syncthreads();

    int lane = t & 63;
    int wid = t >> 6;
    int quad = lane >> 4;
    int l15 = lane & 15;

    f32x4 acc[4];
#pragma unroll
    for (int cg_ = 0; cg_ < 4; cg_++) acc[cg_] = (f32x4){0.f, 0.f, 0.f, 0.f};

    const unsigned short* xrow = &xs[(wid * 16 + l15) * XS + quad * 8];
#pragma unroll
    for (int kc = 0; kc < K / 32; kc++) {
        bf16x8 bfrag = *(const bf16x8*)(xrow + kc * 32);
#pragma unroll
        for (int cg_ = 0; cg_ < 4; cg_++) {
            bf16x8 afrag = *(const bf16x8*)&wt[(cg_ * 16 + l15) * XS + kc * 32 + quad * 8];
            acc[cg_] = __builtin_amdgcn_mfma_f32_16x16x32_bf16(afrag, bfrag, acc[cg_], 0, 0, 0);
        }
    }

    int grow = row0 + wid * 16 + l15;
    if (grow < n) {
        float dv = dinv[grow];
#pragma unroll
        for (int cg_ = 0; cg_ < 4; cg_++) {
            ushort4 st;
            st.x = f2bf(acc[cg_][0] * dv);
            st.y = f2bf(acc[cg_][1] * dv);
            st.z = f2bf(acc[cg_][2] * dv);
            st.w = f2bf(acc[cg_][3] * dv);
            *(ushort4*)&outbf[(size_t)grow * 64 + cg_ * 16 + quad * 4] = st;
        }
    }
}

// ---------------- aggregation + bias + BN + ReLU (uniform CSR walk) --------
// Rows are x4 padded (sentinel entries gather the zeroed sentinel row).
// i/rs/re/csr-entries scalarized via readfirstlane -> CSR reads go through
// the SMEM pipe; gathers use 32-bit voffset (1 VALU each).
__global__ __launch_bounds__(256) void agg_kernel(
        const unsigned short* __restrict__ hs, const int* __restrict__ row_start,
        const int* __restrict__ csr, const float* __restrict__ dinv,
        const float* __restrict__ bias, const float* __restrict__ gam,
        const float* __restrict__ bet, const float* __restrict__ mu,
        const float* __restrict__ var,
        unsigned short* __restrict__ out, int n) {
    int iw = blockIdx.x * 4 + (threadIdx.x >> 6);
    unsigned lane = threadIdx.x & 63;
    if (iw >= n) return;                            // wave-uniform exit
    int i = __builtin_amdgcn_readfirstlane(iw);
    float acc = bf2f(hs[((unsigned)i << 6) + lane]); // self-loop (pre-scaled)
    int rs = __builtin_amdgcn_readfirstlane(row_start[i]);
    int re = __builtin_amdgcn_readfirstlane(row_start[i + 1]);  // x4 padded
    int j = rs;
    for (; j + 16 <= re; j += 16) {
        int s0 = __builtin_amdgcn_readfirstlane(csr[j + 0]);
        int s1 = __builtin_amdgcn_readfirstlane(csr[j + 1]);
        int s2 = __builtin_amdgcn_readfirstlane(csr[j + 2]);
        int s3 = __builtin_amdgcn_readfirstlane(csr[j + 3]);
        int s4 = __builtin_amdgcn_readfirstlane(csr[j + 4]);
        int s5 = __builtin_amdgcn_readfirstlane(csr[j + 5]);
        int s6 = __builtin_amdgcn_readfirstlane(csr[j + 6]);
        int s7 = __builtin_amdgcn_readfirstlane(csr[j + 7]);
        int s8 = __builtin_amdgcn_readfirstlane(csr[j + 8]);
        int s9 = __builtin_amdgcn_readfirstlane(csr[j + 9]);
        int sA = __builtin_amdgcn_readfirstlane(csr[j + 10]);
        int sB = __builtin_amdgcn_readfirstlane(csr[j + 11]);
        int sC = __builtin_amdgcn_readfirstlane(csr[j + 12]);
        int sD = __builtin_amdgcn_readfirstlane(csr[j + 13]);
        int sE = __builtin_amdgcn_readfirstlane(csr[j + 14]);
        int sF = __builtin_amdgcn_readfirstlane(csr[j + 15]);
        float h0 = bf2f(hs[((unsigned)s0 << 6) + lane]);
        float h1 = bf2f(hs[((unsigned)s1 << 6) + lane]);
        float h2 = bf2f(hs[((unsigned)s2 << 6) + lane]);
        float h3 = bf2f(hs[((unsigned)s3 << 6) + lane]);
        float h4 = bf2f(hs[((unsigned)s4 << 6) + lane]);
        float h5 = bf2f(hs[((unsigned)s5 << 6) + lane]);
        float h6 = bf2f(hs[((unsigned)s6 << 6) + lane]);
        float h7 = bf2f(hs[((unsigned)s7 << 6) + lane]);
        float h8 = bf2f(hs[((unsigned)s8 << 6) + lane]);
        float h9 = bf2f(hs[((unsigned)s9 << 6) + lane]);
        float hA = bf2f(hs[((unsigned)sA << 6) + lane]);
        float hB = bf2f(hs[((unsigned)sB << 6) + lane]);
        float hC = bf2f(hs[((unsigned)sC << 6) + lane]);
        float hD = bf2f(hs[((unsigned)sD << 6) + lane]);
        float hE = bf2f(hs[((unsigned)sE << 6) + lane]);
        float hF = bf2f(hs[((unsigned)sF << 6) + lane]);
        acc += (((h0 + h1) + (h2 + h3)) + ((h4 + h5) + (h6 + h7)))
             + (((h8 + h9) + (hA + hB)) + ((hC + hD) + (hE + hF)));
    }
    for (; j < re; j += 4) {
        int s0 = __builtin_amdgcn_readfirstlane(csr[j + 0]);
        int s1 = __builtin_amdgcn_readfirstlane(csr[j + 1]);
        int s2 = __builtin_amdgcn_readfirstlane(csr[j + 2]);
        int s3 = __builtin_amdgcn_readfirstlane(csr[j + 3]);
        float h0 = bf2f(hs[((unsigned)s0 << 6) + lane]);
        float h1 = bf2f(hs[((unsigned)s1 << 6) + lane]);
        float h2 = bf2f(hs[((unsigned)s2 << 6) + lane]);
        float h3 = bf2f(hs[((unsigned)s3 << 6) + lane]);
        acc += (h0 + h1) + (h2 + h3);
    }
    float agg = acc * dinv[i];
    float scale = gam[lane] * rsqrtf(var[lane] + BN_EPS);
    float r = (agg + bias[lane] - mu[lane]) * scale + bet[lane];
    out[((unsigned)i << 6) + lane] = f2bf(r > 0.f ? r : 0.f);
}

// ---------------- pool stage 1: node-parallel segmented sum (bf16 in) ------
#define POOL_CHUNK 64
__global__ __launch_bounds__(256) void pool_kernel(const unsigned short* __restrict__ h,
                                                   const int* __restrict__ batch,
                                                   float* __restrict__ pooled, int n) {
    int wid = blockIdx.x * 4 + (threadIdx.x >> 6);
    int lane = threadIdx.x & 63;
    int start = wid * POOL_CHUNK;
    if (start >= n) return;
    int end = start + POOL_CHUNK; if (end > n) end = n;
    int cur = batch[start];
    float acc = 0.f;
    for (int i = start; i < end; i++) {
        int b = batch[i];
        if (b != cur) {
            atomicAdd(&pooled[(size_t)cur * 64 + lane], acc);
            acc = 0.f; cur = b;
        }
        acc += bf2f(h[(size_t)i * 64 + lane]);
    }
    atomicAdd(&pooled[(size_t)cur * 64 + lane], acc);
}

// ---------------- pool stage 2: tiny MLP per graph ----------------
__global__ void mlp_kernel(const float* __restrict__ pooled,
                           const float* __restrict__ l1w, const float* __restrict__ l1b,
                           const float* __restrict__ l2w, const float* __restrict__ l2b,
                           float* __restrict__ out) {
    int g = blockIdx.x;
    int lane = threadIdx.x;
    __shared__ float p[64];
    __shared__ float h1[32];
    p[lane] = pooled[(size_t)g * 64 + lane];
    __syncthreads();
    if (lane < 32) {
        float a = l1b[lane];
#pragma unroll 8
        for (int k = 0; k < 64; k++) a += p[k] * l1w[k * 32 + lane];
        h1[lane] = a > 0.f ? a : 0.f;
    }
    __syncthreads();
    if (lane < 2) {
        float a = l2b[lane];
#pragma unroll 8
        for (int j = 0; j < 32; j++) a += h1[j] * l2w[j * 2 + lane];
        out[g * 2 + lane] = a;
    }
}

extern "C" void kernel_launch(void* const* d_in, const int* in_sizes, int n_in,
                              void* d_out, int out_size, void* d_ws, size_t ws_size,
                              hipStream_t stream) {
    const float* x     = (const float*)d_in[0];
    const int*   ei    = (const int*)d_in[1];
    const int*   batch = (const int*)d_in[2];
    const float* w0 = (const float*)d_in[3];
    const float* b0 = (const float*)d_in[4];
    const float* w1 = (const float*)d_in[5];
    const float* b1 = (const float*)d_in[6];
    const float* w2 = (const float*)d_in[7];
    const float* b2 = (const float*)d_in[8];
    const float* g0 = (const float*)d_in[9];
    const float* be0 = (const float*)d_in[10];
    const float* m0 = (const float*)d_in[11];
    const float* v0 = (const float*)d_in[12];
    const float* g1 = (const float*)d_in[13];
    const float* be1 = (const float*)d_in[14];
    const float* m1 = (const float*)d_in[15];
    const float* v1 = (const float*)d_in[16];
    const float* g2 = (const float*)d_in[17];
    const float* be2 = (const float*)d_in[18];
    const float* m2 = (const float*)d_in[19];
    const float* v2 = (const float*)d_in[20];
    const float* l1w = (const float*)d_in[21];
    const float* l1b = (const float*)d_in[22];
    const float* l2w = (const float*)d_in[23];
    const float* l2b = (const float*)d_in[24];
    float* out = (float*)d_out;

    const int N = in_sizes[2];
    const int E = in_sizes[1] / 2;
    const int G = out_size / 2;
    const int NBINS = (N + BIN_NODES - 1) / BIN_NODES;
    // fixed per-bin edge capacity: 2x the mean (+45 sigma for Poisson bins)
    int ECAP = ((2 * (E / NBINS)) + 1023) & ~1023;
    if (ECAP < 2048) ECAP = 2048;

    const int* src = ei;
    const int* dst = ei + E;

    // workspace layout
    char* p = (char*)d_ws;
    auto alloc = [&](size_t bytes) -> void* {
        void* r = (void*)p;
        p += (bytes + 255) & ~(size_t)255;
        return r;
    };
    const size_t CSR_CAP = (size_t)E + 4 * (size_t)N + 64;
    float* dinvp    = (float*)alloc((size_t)N * 4);
    int*   row_start= (int*)alloc((size_t)(N + 1) * 4);
    int*   row_local= (int*)alloc((size_t)NBINS * BIN_NODES * 4);
    int*   binpad   = (int*)alloc((size_t)NBINS * 4);
    int*   binbase  = (int*)alloc((size_t)(NBINS + 1) * 4);
    int*   gcursor  = (int*)alloc((size_t)N * 4);
    int*   bincur   = (int*)alloc((size_t)NBINS * 4);      // | contiguous zero
    float* pooled   = (float*)alloc((size_t)G * 64 * 4);   // | region
    char*  zero_end = p;
    int*   ebuf     = (int*)alloc((size_t)NBINS * ECAP * 4);
    int*   csr      = (int*)alloc(CSR_CAP * 4);
    unsigned short* h_a = (unsigned short*)alloc((size_t)(N + 1) * 64 * 2); // +sentinel row
    unsigned short* h_b = (unsigned short*)alloc((size_t)N * 64 * 2);
    (void)ws_size;

    // ---- graph preprocessing (4 launches + 1 memset) ----
    hipMemsetAsync(bincur, 0, (size_t)(zero_end - (char*)bincur), stream);
    const int nchunks = (E + P1_CHUNK - 1) / P1_CHUNK;
    phase1_kernel<<<nchunks, P1_THREADS, 0, stream>>>(src, dst, bincur, ebuf, E, ECAP);
    bincount_kernel<<<NBINS, 1024, 0, stream>>>(ebuf, bincur, ECAP, dinvp,
                                                row_local, binpad,
                                                h_a + (size_t)N * 64, N);
    scan_block_exclusive<<<1, 256, 0, stream>>>(binpad, binbase, NBINS);
    phase2_kernel<<<NBINS, P2_THREADS, 0, stream>>>(ebuf, bincur, ECAP, row_local,
                                                    binbase, row_start, csr,
                                                    gcursor, N, NBINS, N);

    const int nblk = (N + 3) / 4;
    const int lblk = (N + 63) / 64;
    // ---- layer 0 ----
    lin_mfma<128, false><<<lblk, 256, 0, stream>>>(x, w0, dinvp, h_a, N);
    agg_kernel<<<nblk, 256, 0, stream>>>(h_a, row_start, csr, dinvp,
                                         b0, g0, be0, m0, v0, h_b, N);
    // ---- layer 1 ----
    lin_mfma<64, true><<<lblk, 256, 0, stream>>>(h_b, w1, dinvp, h_a, N);
    agg_kernel<<<nblk, 256, 0, stream>>>(h_a, row_start, csr, dinvp,
                                         b1, g1, be1, m1, v1, h_b, N);
    // ---- layer 2 ----
    lin_mfma<64, true><<<lblk, 256, 0, stream>>>(h_b, w2, dinvp, h_a, N);
    agg_kernel<<<nblk, 256, 0, stream>>>(h_a, row_start, csr, dinvp,
                                         b2, g2, be2, m2, v2, h_b, N);
    // ---- pool + MLP ----
    const int pwaves = (N + POOL_CHUNK - 1) / POOL_CHUNK;
    pool_kernel<<<(pwaves + 3) / 4, 256, 0, stream>>>(h_b, batch, pooled, N);
    mlp_kernel<<<G, 64, 0, stream>>>(pooled, l1w, l1b, l2w, l2b, out);
}